// Round 9
// baseline (221.834 us; speedup 1.0000x reference)
//
#include <hip/hip_runtime.h>

#define IMW 1024
#define IMH 1024
#define NB  8
#define HALF 25
#define STRIP 32
#define NCELL 64

#define W_R ((double)0.2989f)
#define W_G ((double)0.5870f)
#define W_B ((double)0.1140f)
#define INV_AREA (1.0 / 2601.0)

__device__ __forceinline__ int refl(int i, int n) {
    if (i < 0) i = -i;
    if (i >= n) i = 2 * n - 2 - i;
    return i;
}

// Transposed LDS index for the per-row cumsum: C[a] lives at (a%16)*64 + a/16.
// Writes (fixed c, lanes t -> phys c*64+t) and wsum tap reads (a = 16t+K,
// K wave-uniform -> phys (K%16)*64 + t + K/16) are both stride-1 across
// lanes: canonical conflict-free, no padding needed (r6/r7 showed padding
// audits of strided f64 layouts are error-prone; stride-1 is provably clean).
__device__ __forceinline__ int tphys(int a) { return (a & 15) * 64 + (a >> 4); }

// 51-window sum at pixel p from inclusive row cumsum in transposed LDS.
__device__ __forceinline__ double twsum(const double* __restrict__ T, int p) {
    int a = p + HALF; if (a > IMW - 1) a = IMW - 1;
    int b = p - HALF - 1;
    double s = T[tphys(a)] - (b >= 0 ? T[tphys(b)] : 0.0);
    if (p <= HALF - 1)      s += T[tphys(HALF - p)] - T[tphys(0)];                        // i<0 mirrored
    if (p >= IMW - HALF)    s += T[tphys(IMW - 2)] - T[tphys(2*IMW - 2 - HALF - 1 - p)];  // i>=IMW mirrored
    return s;
}

// init 64 min-cells (all-ones) and 64 max-cells (zero); g>=0 so f32 bit-order == uint order
__global__ void k0_init(unsigned* cells) {
    cells[threadIdx.x] = (threadIdx.x < NCELL) ? 0xFFFFFFFFu : 0u;
}

// Wave-per-row cumsum pass: one 64-lane wave owns one row, lane owns 16 px.
// Per-lane serial f64 prefix (registers) -> 6-step wave scan of lane totals ->
// transposed-LDS cumsum -> batched independent wsum tap reads. ZERO barriers
// across waves, zero cross-wave coupling (k1's measured bottleneck was the
// serial scan+barrier skeleton: VALUBusy 22%, HBM 31%, nothing saturated).
// 16.4 KB LDS -> ~10 independent waves/CU. Same f64 cumsum numerics as the
// proven scan version (summation order differs by ~1e-13 on h~17; f32 store
// rounding at 1e-6 already proven harmless, absmax 0.0 in r1-r7).
__global__ __launch_bounds__(64) void k1_rowpass(const float* __restrict__ in,
                                                 float2* __restrict__ hp,
                                                 float* __restrict__ gray,
                                                 unsigned* __restrict__ cells) {
    __shared__ double T1[IMW];
    __shared__ double T2[IMW];
    const int t = threadIdx.x;              // lane 0..63
    const int row = blockIdx.x;             // 0 .. NB*IMH-1
    const long long base = (long long)row * IMW;
    const int p0 = 16 * t;

    // ---- 16 px RGB = 12 float4 loads (192B-stride lanes; L1 merges) ----
    const float4* p4 = (const float4*)(in + base * 3);
    float g[16];
    #pragma unroll
    for (int k = 0; k < 4; k++) {
        float4 a = p4[12*t + 3*k + 0];
        float4 b = p4[12*t + 3*k + 1];
        float4 c = p4[12*t + 3*k + 2];
        g[4*k+0] = (float)((double)a.x*W_R + (double)a.y*W_G + (double)a.z*W_B);
        g[4*k+1] = (float)((double)a.w*W_R + (double)b.x*W_G + (double)b.y*W_B);
        g[4*k+2] = (float)((double)b.z*W_R + (double)b.w*W_G + (double)c.x*W_B);
        g[4*k+3] = (float)((double)c.y*W_R + (double)c.z*W_G + (double)c.w*W_B);
    }
    #pragma unroll
    for (int k = 0; k < 4; k++)
        ((float4*)(gray + base))[4*t + k] =
            make_float4(g[4*k+0], g[4*k+1], g[4*k+2], g[4*k+3]);

    // ---- per-wave min/max (f32) -> hierarchical atomic cells ----
    float lmin = g[0], lmax = g[0];
    #pragma unroll
    for (int j = 1; j < 16; j++) { lmin = fminf(lmin, g[j]); lmax = fmaxf(lmax, g[j]); }
    for (int off = 32; off; off >>= 1) {
        lmin = fminf(lmin, __shfl_down(lmin, off));
        lmax = fmaxf(lmax, __shfl_down(lmax, off));
    }
    if (t == 0) {
        int cell = row & (NCELL - 1);
        atomicMin(&cells[cell], __float_as_uint(lmin));
        atomicMax(&cells[NCELL + cell], __float_as_uint(lmax));
    }

    // ---- per-lane serial inclusive prefix (registers) ----
    double C1[16], C2[16];
    double v1 = 0.0, v2 = 0.0;
    #pragma unroll
    for (int j = 0; j < 16; j++) {
        double d = (double)g[j];
        v1 += d; v2 = fma(d, d, v2);
        C1[j] = v1; C2[j] = v2;
    }

    // ---- wave scan of lane totals -> exclusive prefix e ----
    double s1 = v1, s2 = v2;
    for (int off = 1; off < 64; off <<= 1) {
        double u1 = __shfl_up(s1, off);
        double u2 = __shfl_up(s2, off);
        if (t >= off) { s1 += u1; s2 += u2; }
    }
    double e1 = s1 - v1, e2 = s2 - v2;

    // ---- write adjusted cumsum, transposed (stride-1 lanes, conflict-free) ----
    #pragma unroll
    for (int j = 0; j < 16; j++) {
        T1[j * 64 + t] = e1 + C1[j];   // tphys(16t+j) = j*64 + t
        T2[j * 64 + t] = e2 + C2[j];
    }
    __syncthreads();   // single-wave block: cheap lgkmcnt drain, orders LDS

    // ---- batched wsum taps + paired float4 hp stores ----
    float hx[16], hy[16];
    #pragma unroll
    for (int j = 0; j < 16; j++) {
        hx[j] = (float)twsum(T1, p0 + j);
        hy[j] = (float)twsum(T2, p0 + j);
    }
    float4* o = (float4*)(hp + base + p0);   // float2 base even -> 16B aligned
    #pragma unroll
    for (int k = 0; k < 8; k++)
        o[k] = make_float4(hx[2*k], hy[2*k], hx[2*k+1], hy[2*k+1]);
}

// Column pass: 1 column/thread, vertical running 51-window over interleaved hp.
// r7-verbatim (measured ~35us): STRIP=32, 1024 blocks = 16 waves/CU, interior
// fast path (no refl, pointer increments, hoisted slide loads) for 30/32
// strips. k2 is logical-byte-throughput-limited at ~6.8 TB/s effective
// (beyond-HBM via L2/L3 hits) -- leave geometry alone.
// Sqrt/div-free Sauvola compare: g > m(1+0.2(s/r-1)) <=> A>0 && A^2 r^2 > 0.04 m^2 var.
__global__ __launch_bounds__(256) void k2_colpass(const float* __restrict__ gray,
                                                  const float2* __restrict__ hp,
                                                  const unsigned* __restrict__ cells,
                                                  float* __restrict__ out) {
    __shared__ double sr[2];
    const int t = threadIdx.x;
    if (t < 64) {
        unsigned mn = cells[t];
        unsigned mx = cells[NCELL + t];
        for (int off = 32; off; off >>= 1) {
            unsigned a = __shfl_down(mn, off);
            unsigned b = __shfl_down(mx, off);
            mn = (a < mn) ? a : mn;
            mx = (b > mx) ? b : mx;
        }
        if (t == 0) {
            sr[0] = (double)__uint_as_float(mn);
            sr[1] = (double)__uint_as_float(mx);
        }
    }
    __syncthreads();
    const double r  = 0.5 * (sr[1] - sr[0]);
    const double r2 = r * r;

    const int id   = blockIdx.x;          // 1024 blocks
    const int b    = id & 7;              // batch -> XCD
    const int rest = id >> 3;
    const int ys   = rest & 31;           // y-strip (consecutive on same XCD)
    const int xc   = rest >> 5;           // x quarter (0..3)
    const int x  = xc * 256 + t;          // 1 column per thread
    const int y0 = ys * STRIP;
    const long long ib = (long long)b * IMH * IMW;

    double vx = 0.0, vy = 0.0;            // {h1,h2} running vertical sums (f64 accum)

    if (ys >= 1 && ys <= 30) {            // ---- interior: no reflection anywhere ----
        const float2* ph = hp + ib + (long long)(y0 - HALF) * IMW + x;
        #pragma unroll 17
        for (int j = 0; j < 51; j++) {    // same accumulation order as refl path
            float2 h = ph[0];
            vx += (double)h.x; vy += (double)h.y;
            ph += IMW;
        }
        const float2* pa = hp + ib + (long long)(y0 + HALF + 1) * IMW + x;
        const float2* ps = hp + ib + (long long)(y0 - HALF) * IMW + x;
        const float*  pg = gray + ib + (long long)y0 * IMW + x;
        float*        po = out  + ib + (long long)y0 * IMW + x;
        #pragma unroll 8
        for (int i = 0; i < STRIP; i++) {
            float2 ha = pa[0];            // hoisted slide loads (prefetch)
            float2 hs = ps[0];
            double g = (double)pg[0];

            double m  = vx * INV_AREA;
            double va = fmax(vy * INV_AREA - m * m, 0.0);
            double A  = g - 0.8 * m;
            int o = (A > 0.0) && (A * A * r2 > 0.04 * m * m * va);
            po[0] = o ? 1.0f : 0.0f;

            vx += (double)ha.x - (double)hs.x;   // same add order as refl path
            vy += (double)ha.y - (double)hs.y;
            pa += IMW; ps += IMW; pg += IMW; po += IMW;
        }
    } else {                              // ---- edge strips: original refl path ----
        #pragma unroll 8
        for (int j = -HALF; j <= HALF; j++) {
            int ry = refl(y0 + j, IMH);
            float2 h = hp[ib + (long long)ry * IMW + x];
            vx += (double)h.x; vy += (double)h.y;
        }
        #pragma unroll 8
        for (int y = y0; y < y0 + STRIP; y++) {
            long long pix = ib + (long long)y * IMW + x;
            double g = (double)gray[pix];

            double m  = vx * INV_AREA;
            double va = fmax(vy * INV_AREA - m * m, 0.0);
            double A  = g - 0.8 * m;
            int o = (A > 0.0) && (A * A * r2 > 0.04 * m * m * va);
            out[pix] = o ? 1.0f : 0.0f;

            int ra = refl(y + HALF + 1, IMH);
            int rs = refl(y - HALF, IMH);
            float2 ha = hp[ib + (long long)ra * IMW + x];
            float2 hs = hp[ib + (long long)rs * IMW + x];
            vx += (double)ha.x - (double)hs.x;
            vy += (double)ha.y - (double)hs.y;
        }
    }
}

extern "C" void kernel_launch(void* const* d_in, const int* in_sizes, int n_in,
                              void* d_out, int out_size, void* d_ws, size_t ws_size,
                              hipStream_t stream) {
    const float* in = (const float*)d_in[0];
    float* out = (float*)d_out;

    unsigned* cells = (unsigned*)d_ws;                          // 2*64 u32
    float2* hp = (float2*)((char*)d_ws + 4096);                 // 67 MB interleaved {h1,h2}
    float* gray = (float*)((char*)d_ws + 4096
                           + (size_t)NB * IMH * IMW * sizeof(float2)); // 33.5 MB staged gray

    hipLaunchKernelGGL(k0_init, dim3(1), dim3(2 * NCELL), 0, stream, cells);
    hipLaunchKernelGGL(k1_rowpass, dim3(NB * IMH), dim3(64), 0, stream,
                       in, hp, gray, cells);
    hipLaunchKernelGGL(k2_colpass, dim3((IMW / 256) * (IMH / STRIP) * NB), dim3(256), 0, stream,
                       gray, hp, cells, out);
}